// Round 11
// baseline (71.454 us; speedup 1.0000x reference)
//
#include <hip/hip_runtime.h>
#include <hip/hip_bf16.h>

// LCN: B=512, C=1, H=W=280, K=S=28, F=10, SPAN=100 (10x10), DEC_IN=1000, OUT=10
// ROUND 11: MEASUREMENT ROUND. Identical to R10 except lcn_conv is launched
// TWICE (deterministic: conv is a pure function of x,wbuf and fully overwrites
// P). delta(total) vs R10 (45.34us) = conv duration + ~2us launch gap.
#define HW      280
#define IMG     78400        // 280*280
#define KK      28
#define F_N     10
#define SPAN    100
#define OUT_N   10
#define P_PLANE 512000       // 1000*512

typedef short s16x8 __attribute__((ext_vector_type(8)));   // 8 bf16 (4 VGPRs)
typedef float f32x4 __attribute__((ext_vector_type(4)));   // MFMA C/D

static __device__ __forceinline__ unsigned bits2(__hip_bfloat162 h) {
  return *reinterpret_cast<unsigned*>(&h);
}

// Raw barrier: LDS visibility only (lgkmcnt), NO vmcnt drain -- global loads
// stay in flight across the barrier (bypasses __syncthreads' vmcnt(0) drain).
#define RAW_BARRIER() asm volatile("s_waitcnt lgkmcnt(0)\ns_barrier" ::: "memory")

// wprep: wbuf[s][r][f 16][k 32] bf16, zero-padded f>=10, k>=28.
// One uint4 (8 bf16) per thread: idx4 = ((s*28+r)*16+f)*4 + k8.
__global__ __launch_bounds__(256) void wprep(const float* __restrict__ cw,
                                             uint4* __restrict__ wbuf4) {
  const int idx = blockIdx.x * 256 + (int)threadIdx.x;  // 0..179199
  const int k8  = idx & 3;
  const int f   = (idx >> 2) & 15;
  const int rs  = idx >> 6;          // r + 28*s
  const int r   = rs % 28;
  const int s   = rs / 28;
  uint4 out = make_uint4(0, 0, 0, 0);
  if (f < F_N) {
    const float* base = cw + (size_t)(f * SPAN + s) * (KK * KK) + r * KK + k8 * 8;
    const float4 a = *reinterpret_cast<const float4*>(base);
    out.x = bits2(__float22bfloat162_rn(make_float2(a.x, a.y)));
    out.y = bits2(__float22bfloat162_rn(make_float2(a.z, a.w)));
    if (k8 < 3) {                    // k8==3 covers k 24..27 only (28..31 pad)
      const float4 c = *reinterpret_cast<const float4*>(base + 4);
      out.z = bits2(__float22bfloat162_rn(make_float2(c.x, c.y)));
      out.w = bits2(__float22bfloat162_rn(make_float2(c.z, c.w)));
    }
  }
  wbuf4[idx] = out;
}

// Conv via MFMA: grid 1280 = bg(32: 16 b) x hs(10) x rq(4: 7 rows).
// Raw lgkm-only barriers + vmcnt-ordered issue (B-frags first, then x
// prefetch row r+2) so the x stream keeps 2 rows in flight across barriers.
__global__ __launch_bounds__(256, 4) void lcn_conv(
    const float* __restrict__ x, const unsigned short* __restrict__ wbuf,
    float* __restrict__ P) {
  const int bid  = blockIdx.x;       // 0..1279
  const int xcd  = bid & 7;
  const int grp  = bid >> 3;         // 0..159
  const int hsrq = xcd + 8 * (grp % 5);  // 0..39, fixed per XCD set
  const int bg   = grp / 5;          // 0..31
  const int hs   = hsrq >> 2;
  const int rq   = hsrq & 3;

  const int tid  = (int)threadIdx.x;
  const int lane = tid & 63;
  const int wid  = tid >> 6;
  const int l15  = lane & 15;
  const int kg   = lane >> 4;        // 0..3

  __shared__ short xl[2][16 * 320];  // 20.5 KB double-buffered A-tile

  // zero the k-pad slots (k 28..31 of each ws), same swizzle as data
  for (int i = tid; i < 2 * 160; i += 256) {
    const int buf = i / 160, j = i - buf * 160;
    const int b = j / 10, ws = j - b * 10;
    const int sidx = (b * 320 + ws * 32 + 28) ^ ((b & 7) << 3);
    *reinterpret_cast<short4*>(&xl[buf][sidx]) = make_short4(0, 0, 0, 0);
  }

  const int nun = (wid < 2) ? 3 : 2;             // ws units per wave (3,3,2,2)
  const int wsl[3] = {wid, wid + 4, wid + 8};    // ws 10/11 read padded wbuf, never MFMA'd

  f32x4 acc[3];
#pragma unroll
  for (int u = 0; u < 3; ++u) acc[u] = (f32x4){0.f, 0.f, 0.f, 0.f};

  const int row0 = hs * KK + rq * 7;
  const float* xbase = x + (size_t)bg * 16 * IMG + (size_t)row0 * HW;

  float4 stgA[5], stgB[5];

#define ISSUE(STG, R)                                                       \
  _Pragma("unroll")                                                         \
  for (int j = 0; j < 5; ++j) {                                             \
    const int i = tid + 256 * j;                                            \
    if (i < 1120) {                                                         \
      const int b = i / 70, q = i - b * 70;                                 \
      STG[j] = *reinterpret_cast<const float4*>(                            \
          xbase + (size_t)b * IMG + (size_t)(R) * HW + q * 4);              \
    }                                                                       \
  }

#define COMMIT(STG, BUF)                                                    \
  _Pragma("unroll")                                                         \
  for (int j = 0; j < 5; ++j) {                                             \
    const int i = tid + 256 * j;                                            \
    if (i < 1120) {                                                         \
      const int b = i / 70, q = i - b * 70;                                 \
      const int ws = q / 7, c4 = q - ws * 7;                                \
      const int sidx = (b * 320 + ws * 32 + c4 * 4) ^ ((b & 7) << 3);       \
      uint2 pk;                                                             \
      pk.x = bits2(__float22bfloat162_rn(make_float2(STG[j].x, STG[j].y))); \
      pk.y = bits2(__float22bfloat162_rn(make_float2(STG[j].z, STG[j].w))); \
      *reinterpret_cast<uint2*>(&xl[BUF][sidx]) = pk;                       \
    }                                                                       \
  }

  // prologue: rows 0 (A) and 1 (B) in flight; commit A; lgkm barrier
  ISSUE(stgA, 0)
  ISSUE(stgB, 1)
  COMMIT(stgA, 0)            // waits A's loads only (B stays in flight)
  RAW_BARRIER();

#pragma unroll
  for (int r = 0; r < 7; ++r) {
    const int buf = r & 1;
    const int rr  = rq * 7 + r;

    // (1) B-frags FIRST (oldest vmem this phase)
    s16x8 bfr[3];
#pragma unroll
    for (int u = 0; u < 3; ++u)
      bfr[u] = *reinterpret_cast<const s16x8*>(
          wbuf + (size_t)((hs * 10 + wsl[u]) * 28 + rr) * 512 + l15 * 32 + kg * 8);

    // (2) x prefetch row r+2 (newest vmem; survives MFMA wait + raw barrier)
    if (r + 2 < 7) {
      if (r & 1) { ISSUE(stgB, r + 2) } else { ISSUE(stgA, r + 2) }
    }

    // (3) MFMA row r from xl[buf]
#pragma unroll
    for (int u = 0; u < 3; ++u) {
      if (u < nun) {
        const int ws = wsl[u];
        const int sidx = (l15 * 320 + ws * 32 + kg * 8) ^ ((l15 & 7) << 3);
        const s16x8 afr = *reinterpret_cast<const s16x8*>(&xl[buf][sidx]);
        acc[u] = __builtin_amdgcn_mfma_f32_16x16x32_bf16(afr, bfr[u], acc[u], 0, 0, 0);
      }
    }

    // (4) commit row r+1 (issued last phase) into buf^1; lgkm-only barrier
    if (r < 6) {
      if (r & 1) { COMMIT(stgA, buf ^ 1) } else { COMMIT(stgB, buf ^ 1) }
      RAW_BARRIER();
    }
  }

  // D layout: row(b-off) = kg*4+j, col(f) = l15. P[rq][f*100+s][b].
  if (l15 < F_N) {
#pragma unroll
    for (int u = 0; u < 3; ++u) {
      if (u < nun) {
        const int s = hs * 10 + wsl[u];
        float* Pp = P + (size_t)rq * P_PLANE + (size_t)(l15 * SPAN + s) * 512
                      + bg * 16 + kg * 4;
        *reinterpret_cast<float4*>(Pp) =
            make_float4(acc[u][0], acc[u][1], acc[u][2], acc[u][3]);
      }
    }
  }
}

// Combine 4 rq quarters + bias + relu + decoder partials. (unchanged)
__global__ __launch_bounds__(512) void lcn_dec(
    const float* __restrict__ P, const float* __restrict__ cb,
    const float* __restrict__ dw, float* __restrict__ yp) {
  const int dchunk = blockIdx.x;        // 0..49
  const int b      = (int)threadIdx.x;  // 0..511

  const float* Pb = P + b;
  float acc[OUT_N];
#pragma unroll
  for (int o = 0; o < OUT_N; ++o) acc[o] = 0.f;

#pragma unroll
  for (int dd = 0; dd < 20; ++dd) {
    const int d = dchunk * 20 + dd;     // wave-uniform
    const float* pd = Pb + (size_t)d * 512;
    const float p = pd[0] + pd[P_PLANE] + pd[2 * (size_t)P_PLANE]
                          + pd[3 * (size_t)P_PLANE];
    const float h = fmaxf(p + cb[d], 0.f);
#pragma unroll
    for (int o = 0; o < OUT_N; ++o)
      acc[o] = fmaf(h, dw[o * 1000 + d], acc[o]);  // wave-uniform -> s_load
  }
#pragma unroll
  for (int o = 0; o < OUT_N; ++o)
    yp[(size_t)(dchunk * OUT_N + o) * 512 + b] = acc[o];
}

// y[b][o] = db[o] + sum over 50 yp planes; grid 40 x 128 (unchanged)
__global__ __launch_bounds__(128) void lcn_yred(
    const float* __restrict__ yp, const float* __restrict__ db,
    float* __restrict__ y) {
  const int idx = blockIdx.x * 128 + (int)threadIdx.x;  // 0..5119 = o*512+b
  const int o = idx >> 9;
  const int b = idx & 511;
  float a = db[o];
#pragma unroll 10
  for (int p = 0; p < 50; ++p) a += yp[(size_t)p * 5120 + idx];
  y[b * OUT_N + o] = a;
}

extern "C" void kernel_launch(void* const* d_in, const int* in_sizes, int n_in,
                              void* d_out, int out_size, void* d_ws, size_t ws_size,
                              hipStream_t stream) {
  const float* x  = (const float*)d_in[0];   // [512,1,280,280]
  const float* cw = (const float*)d_in[1];   // [1000,1,28,28]
  const float* cb = (const float*)d_in[2];   // [1000,1]
  const float* dw = (const float*)d_in[3];   // [10,1000]
  const float* db = (const float*)d_in[4];   // [10]
  float* y = (float*)d_out;                  // [512,10]

  float*    P    = (float*)d_ws;                       // [4][1000][512] = 8.192 MB
  float*    yp   = P + 4 * (size_t)P_PLANE;            // [50][10][512]  = 1.024 MB
  uint4*    wbuf = (uint4*)(yp + 50 * 5120);           // [102][28][16][16]u32 (2 pad s-slots)

  wprep   <<<dim3(700),  dim3(256), 0, stream>>>(cw, wbuf);
  lcn_conv<<<dim3(1280), dim3(256), 0, stream>>>(x, (const unsigned short*)wbuf, P);
  lcn_conv<<<dim3(1280), dim3(256), 0, stream>>>(x, (const unsigned short*)wbuf, P);  // DUP: measures conv
  lcn_dec <<<dim3(50),   dim3(512), 0, stream>>>(P, cb, dw, yp);
  lcn_yred<<<dim3(40),   dim3(128), 0, stream>>>(yp, db, y);
}

// Round 12
// 43.526 us; speedup vs baseline: 1.6416x; 1.6416x over previous
//
#include <hip/hip_runtime.h>
#include <hip/hip_bf16.h>

// LCN: B=512, C=1, H=W=280, K=S=28, F=10, SPAN=100 (10x10), DEC_IN=1000, OUT=10
// ROUND 12: conv measured AT stream roofline (~25us = 160.6MB @ 6.5TB/s, R11
// dup-ablation). This round slims the aux kernels (~13us of the remaining ~20):
// wprep -> fully linear reads; dec -> 200 blocks; yred -> 25 planes.
#define HW      280
#define IMG     78400        // 280*280
#define KK      28
#define F_N     10
#define SPAN    100
#define OUT_N   10
#define P_PLANE 512000       // 1000*512

typedef short s16x8 __attribute__((ext_vector_type(8)));   // 8 bf16 (4 VGPRs)
typedef float f32x4 __attribute__((ext_vector_type(4)));   // MFMA C/D

static __device__ __forceinline__ unsigned bits2(__hip_bfloat162 h) {
  return *reinterpret_cast<unsigned*>(&h);
}

// Raw barrier: LDS visibility only (lgkmcnt), NO vmcnt drain -- global loads
// stay in flight across the barrier (bypasses __syncthreads' vmcnt(0) drain).
#define RAW_BARRIER() asm volatile("s_waitcnt lgkmcnt(0)\ns_barrier" ::: "memory")

// wprep: wbuf[s][r][f 16][k 32] bf16 (k 28..31 zero; f 10..15 left unwritten --
// conv's dummy-unit reads of f>=10 / s>=100 are never fed to MFMA).
// Thread = one (f,s,r) row: idx = (f*100+s)*28 + r -> src = cw + idx*28 is
// PERFECTLY LINEAR (wave reads 7KB contiguous); writes 64B contiguous/thread.
__global__ __launch_bounds__(256) void wprep(const float* __restrict__ cw,
                                             uint4* __restrict__ wbuf4) {
  const int idx = blockIdx.x * 256 + (int)threadIdx.x;  // 0..27999
  if (idx >= 28000) return;
  const int fs = idx / 28;          // f*100 + s
  const int r  = idx - fs * 28;
  const int f  = fs / 100;
  const int s  = fs - f * 100;

  const float* src = cw + (size_t)idx * 28;   // 112B, 16B-aligned
  float v[28];
#pragma unroll
  for (int j = 0; j < 7; ++j)
    *reinterpret_cast<float4*>(&v[j * 4]) =
        *reinterpret_cast<const float4*>(src + j * 4);

  unsigned p[16];
#pragma unroll
  for (int k2 = 0; k2 < 14; ++k2)
    p[k2] = bits2(__float22bfloat162_rn(make_float2(v[2 * k2], v[2 * k2 + 1])));
  p[14] = 0u; p[15] = 0u;

  uint4* dst = wbuf4 + ((size_t)(s * 28 + r) * 16 + f) * 4;  // 64B aligned
  dst[0] = make_uint4(p[0],  p[1],  p[2],  p[3]);
  dst[1] = make_uint4(p[4],  p[5],  p[6],  p[7]);
  dst[2] = make_uint4(p[8],  p[9],  p[10], p[11]);
  dst[3] = make_uint4(p[12], p[13], p[14], p[15]);
}

// Conv via MFMA: grid 1280 = bg(32: 16 b) x hs(10) x rq(4: 7 rows).
// UNCHANGED from R10 (measured at stream roofline: ~25us = 6.5 TB/s).
__global__ __launch_bounds__(256, 4) void lcn_conv(
    const float* __restrict__ x, const unsigned short* __restrict__ wbuf,
    float* __restrict__ P) {
  const int bid  = blockIdx.x;       // 0..1279
  const int xcd  = bid & 7;
  const int grp  = bid >> 3;         // 0..159
  const int hsrq = xcd + 8 * (grp % 5);  // 0..39, fixed per XCD set
  const int bg   = grp / 5;          // 0..31
  const int hs   = hsrq >> 2;
  const int rq   = hsrq & 3;

  const int tid  = (int)threadIdx.x;
  const int lane = tid & 63;
  const int wid  = tid >> 6;
  const int l15  = lane & 15;
  const int kg   = lane >> 4;        // 0..3

  __shared__ short xl[2][16 * 320];  // 20.5 KB double-buffered A-tile

  // zero the k-pad slots (k 28..31 of each ws), same swizzle as data
  for (int i = tid; i < 2 * 160; i += 256) {
    const int buf = i / 160, j = i - buf * 160;
    const int b = j / 10, ws = j - b * 10;
    const int sidx = (b * 320 + ws * 32 + 28) ^ ((b & 7) << 3);
    *reinterpret_cast<short4*>(&xl[buf][sidx]) = make_short4(0, 0, 0, 0);
  }

  const int nun = (wid < 2) ? 3 : 2;             // ws units per wave (3,3,2,2)
  const int wsl[3] = {wid, wid + 4, wid + 8};    // ws 10/11 hit pad region, never MFMA'd

  f32x4 acc[3];
#pragma unroll
  for (int u = 0; u < 3; ++u) acc[u] = (f32x4){0.f, 0.f, 0.f, 0.f};

  const int row0 = hs * KK + rq * 7;
  const float* xbase = x + (size_t)bg * 16 * IMG + (size_t)row0 * HW;

  float4 stgA[5], stgB[5];

#define ISSUE(STG, R)                                                       \
  _Pragma("unroll")                                                         \
  for (int j = 0; j < 5; ++j) {                                             \
    const int i = tid + 256 * j;                                            \
    if (i < 1120) {                                                         \
      const int b = i / 70, q = i - b * 70;                                 \
      STG[j] = *reinterpret_cast<const float4*>(                            \
          xbase + (size_t)b * IMG + (size_t)(R) * HW + q * 4);              \
    }                                                                       \
  }

#define COMMIT(STG, BUF)                                                    \
  _Pragma("unroll")                                                         \
  for (int j = 0; j < 5; ++j) {                                             \
    const int i = tid + 256 * j;                                            \
    if (i < 1120) {                                                         \
      const int b = i / 70, q = i - b * 70;                                 \
      const int ws = q / 7, c4 = q - ws * 7;                                \
      const int sidx = (b * 320 + ws * 32 + c4 * 4) ^ ((b & 7) << 3);       \
      uint2 pk;                                                             \
      pk.x = bits2(__float22bfloat162_rn(make_float2(STG[j].x, STG[j].y))); \
      pk.y = bits2(__float22bfloat162_rn(make_float2(STG[j].z, STG[j].w))); \
      *reinterpret_cast<uint2*>(&xl[BUF][sidx]) = pk;                       \
    }                                                                       \
  }

  // prologue: rows 0 (A) and 1 (B) in flight; commit A; lgkm barrier
  ISSUE(stgA, 0)
  ISSUE(stgB, 1)
  COMMIT(stgA, 0)            // waits A's loads only (B stays in flight)
  RAW_BARRIER();

#pragma unroll
  for (int r = 0; r < 7; ++r) {
    const int buf = r & 1;
    const int rr  = rq * 7 + r;

    // (1) B-frags FIRST (oldest vmem this phase)
    s16x8 bfr[3];
#pragma unroll
    for (int u = 0; u < 3; ++u)
      bfr[u] = *reinterpret_cast<const s16x8*>(
          wbuf + (size_t)((hs * 10 + wsl[u]) * 28 + rr) * 512 + l15 * 32 + kg * 8);

    // (2) x prefetch row r+2 (newest vmem; survives MFMA wait + raw barrier)
    if (r + 2 < 7) {
      if (r & 1) { ISSUE(stgB, r + 2) } else { ISSUE(stgA, r + 2) }
    }

    // (3) MFMA row r from xl[buf]
#pragma unroll
    for (int u = 0; u < 3; ++u) {
      if (u < nun) {
        const int ws = wsl[u];
        const int sidx = (l15 * 320 + ws * 32 + kg * 8) ^ ((l15 & 7) << 3);
        const s16x8 afr = *reinterpret_cast<const s16x8*>(&xl[buf][sidx]);
        acc[u] = __builtin_amdgcn_mfma_f32_16x16x32_bf16(afr, bfr[u], acc[u], 0, 0, 0);
      }
    }

    // (4) commit row r+1 (issued last phase) into buf^1; lgkm-only barrier
    if (r < 6) {
      if (r & 1) { COMMIT(stgA, buf ^ 1) } else { COMMIT(stgB, buf ^ 1) }
      RAW_BARRIER();
    }
  }

  // D layout: row(b-off) = kg*4+j, col(f) = l15. P[rq][f*100+s][b].
  if (l15 < F_N) {
#pragma unroll
    for (int u = 0; u < 3; ++u) {
      if (u < nun) {
        const int s = hs * 10 + wsl[u];
        float* Pp = P + (size_t)rq * P_PLANE + (size_t)(l15 * SPAN + s) * 512
                      + bg * 16 + kg * 4;
        *reinterpret_cast<float4*>(Pp) =
            make_float4(acc[u][0], acc[u][1], acc[u][2], acc[u][3]);
      }
    }
  }
}

// Combine 4 rq quarters + bias + relu + decoder partials.
// ROUND 12: grid 200 = dchunk(25: 40 d) x bgroup(8: 64 b); 256 thr =
// 4 d-ways x 64 b; each thread 10 d; LDS-reduce the 4 d-ways.
// yp[25][10][512] (512 KB).
__global__ __launch_bounds__(256) void lcn_dec(
    const float* __restrict__ P, const float* __restrict__ cb,
    const float* __restrict__ dw, float* __restrict__ yp) {
  const int dchunk = blockIdx.x >> 3;    // 0..24
  const int bgrp   = blockIdx.x & 7;     // 0..7
  const int tid    = (int)threadIdx.x;
  const int bl     = tid & 63;
  const int dway   = tid >> 6;           // 0..3 (wave id -> wave-uniform d)
  const int b      = bgrp * 64 + bl;

  const float* Pb = P + b;
  float acc[OUT_N];
#pragma unroll
  for (int o = 0; o < OUT_N; ++o) acc[o] = 0.f;

#pragma unroll
  for (int dd = 0; dd < 10; ++dd) {
    const int d = dchunk * 40 + dway * 10 + dd;   // wave-uniform
    const float* pd = Pb + (size_t)d * 512;
    const float p = pd[0] + pd[P_PLANE] + pd[2 * (size_t)P_PLANE]
                          + pd[3 * (size_t)P_PLANE];
    const float h = fmaxf(p + cb[d], 0.f);
#pragma unroll
    for (int o = 0; o < OUT_N; ++o)
      acc[o] = fmaf(h, dw[o * 1000 + d], acc[o]);  // wave-uniform -> s_load
  }

  __shared__ float red[3][OUT_N][64];
  if (dway > 0) {
#pragma unroll
    for (int o = 0; o < OUT_N; ++o) red[dway - 1][o][bl] = acc[o];
  }
  __syncthreads();
  if (dway == 0) {
#pragma unroll
    for (int o = 0; o < OUT_N; ++o) {
      const float v = acc[o] + red[0][o][bl] + red[1][o][bl] + red[2][o][bl];
      yp[(size_t)(dchunk * OUT_N + o) * 512 + b] = v;   // coalesced over b
    }
  }
}

// y[b][o] = db[o] + sum over 25 yp planes; grid 20 x 256 (5120 outputs)
__global__ __launch_bounds__(256) void lcn_yred(
    const float* __restrict__ yp, const float* __restrict__ db,
    float* __restrict__ y) {
  const int idx = blockIdx.x * 256 + (int)threadIdx.x;  // 0..5119 = o*512+b
  const int o = idx >> 9;
  const int b = idx & 511;
  float a = db[o];
#pragma unroll
  for (int p = 0; p < 25; ++p) a += yp[(size_t)p * 5120 + idx];  // coalesced
  y[b * OUT_N + o] = a;
}

extern "C" void kernel_launch(void* const* d_in, const int* in_sizes, int n_in,
                              void* d_out, int out_size, void* d_ws, size_t ws_size,
                              hipStream_t stream) {
  const float* x  = (const float*)d_in[0];   // [512,1,280,280]
  const float* cw = (const float*)d_in[1];   // [1000,1,28,28]
  const float* cb = (const float*)d_in[2];   // [1000,1]
  const float* dw = (const float*)d_in[3];   // [10,1000]
  const float* db = (const float*)d_in[4];   // [10]
  float* y = (float*)d_out;                  // [512,10]

  float* P  = (float*)d_ws;                  // [4][1000][512] = 8.192 MB
  float* yp = P + 4 * (size_t)P_PLANE;       // [25][10][512]  = 0.512 MB
  uint4* wbuf = (uint4*)(yp + 25 * 5120);    // [102][28][16][16]u32 = 2.92 MB

  wprep   <<<dim3(110),  dim3(256), 0, stream>>>(cw, wbuf);
  lcn_conv<<<dim3(1280), dim3(256), 0, stream>>>(x, (const unsigned short*)wbuf, P);
  lcn_dec <<<dim3(200),  dim3(256), 0, stream>>>(P, cb, dw, yp);
  lcn_yred<<<dim3(20),   dim3(256), 0, stream>>>(yp, db, y);
}

// Round 13
// 42.047 us; speedup vs baseline: 1.6994x; 1.0352x over previous
//
#include <hip/hip_runtime.h>
#include <hip/hip_bf16.h>

// LCN: B=512, C=1, H=W=280, K=S=28, F=10, SPAN=100 (10x10), DEC_IN=1000, OUT=10
// ROUND 13: eliminate P + dec. conv = bg(32) x hs(10) = 320 blocks, all 28
// rows in MFMA accumulators, fused bias+relu+decoder epilogue -> yp[hs][o][b].
// Saves: 16.6 MB P round-trip, one dispatch + gap, dec kernel.
#define HW      280
#define IMG     78400        // 280*280
#define KK      28
#define F_N     10
#define SPAN    100
#define OUT_N   10

typedef short s16x8 __attribute__((ext_vector_type(8)));   // 8 bf16 (4 VGPRs)
typedef float f32x4 __attribute__((ext_vector_type(4)));   // MFMA C/D

static __device__ __forceinline__ unsigned bits2(__hip_bfloat162 h) {
  return *reinterpret_cast<unsigned*>(&h);
}

// Raw barrier: LDS visibility only (lgkmcnt), NO vmcnt drain -- global loads
// stay in flight across the barrier (bypasses __syncthreads' vmcnt(0) drain).
#define RAW_BARRIER() asm volatile("s_waitcnt lgkmcnt(0)\ns_barrier" ::: "memory")

// wprep: wbuf[s][r][f 16][k 32] bf16 (k 28..31 zero; f 10..15 unwritten --
// dummy-unit reads of s>=100 hit the 2 pad s-slots, never fed to MFMA).
// Thread = one (f,s,r) row: src = cw + idx*28 is PERFECTLY LINEAR.
__global__ __launch_bounds__(256) void wprep(const float* __restrict__ cw,
                                             uint4* __restrict__ wbuf4) {
  const int idx = blockIdx.x * 256 + (int)threadIdx.x;  // 0..27999
  if (idx >= 28000) return;
  const int fs = idx / 28;          // f*100 + s
  const int r  = idx - fs * 28;
  const int f  = fs / 100;
  const int s  = fs - f * 100;

  const float* src = cw + (size_t)idx * 28;   // 112B, 16B-aligned
  float v[28];
#pragma unroll
  for (int j = 0; j < 7; ++j)
    *reinterpret_cast<float4*>(&v[j * 4]) =
        *reinterpret_cast<const float4*>(src + j * 4);

  unsigned p[16];
#pragma unroll
  for (int k2 = 0; k2 < 14; ++k2)
    p[k2] = bits2(__float22bfloat162_rn(make_float2(v[2 * k2], v[2 * k2 + 1])));
  p[14] = 0u; p[15] = 0u;

  uint4* dst = wbuf4 + ((size_t)(s * 28 + r) * 16 + f) * 4;  // 64B aligned
  dst[0] = make_uint4(p[0],  p[1],  p[2],  p[3]);
  dst[1] = make_uint4(p[4],  p[5],  p[6],  p[7]);
  dst[2] = make_uint4(p[8],  p[9],  p[10], p[11]);
  dst[3] = make_uint4(p[12], p[13], p[14], p[15]);
}

// Fused conv+bias+relu+decoder. grid 320 = bg(32: 16 b) x hs(10).
// Row pipeline identical to the rooflined R10 loop (raw lgkm barriers,
// B-frags oldest, x prefetch depth 2), 28 rows, K=784 stays in accumulators.
// Epilogue: D-frags -> h_lds[100 d][16 b]; 160 threads do the per-(b,o)
// decoder dot from LDS -> yp[hs*10+o][512].
__global__ __launch_bounds__(256, 4) void lcn_conv(
    const float* __restrict__ x, const unsigned short* __restrict__ wbuf,
    const float* __restrict__ cb, const float* __restrict__ dw,
    float* __restrict__ yp) {
  const int bid = blockIdx.x;        // 0..319
  const int hs  = bid % 10;
  const int bg  = bid / 10;          // 0..31

  const int tid  = (int)threadIdx.x;
  const int lane = tid & 63;
  const int wid  = tid >> 6;
  const int l15  = lane & 15;
  const int kg   = lane >> 4;        // 0..3

  __shared__ short xl[2][16 * 320];  // 20.5 KB double-buffered A-tile
  __shared__ float h_lds[100 * 16];  // relu'd conv out [d=f*10+ws][b16]
  __shared__ float dw_lds[1000];     // dw slice [o][f*10+ws] for this hs

  // stage dw slice (visibility covered by the prologue barrier + final sync)
  for (int i = tid; i < 1000; i += 256) {
    const int o  = i / 100, dl = i - o * 100;
    const int f  = dl / 10, ws = dl - f * 10;
    dw_lds[i] = dw[o * 1000 + f * 100 + hs * 10 + ws];
  }

  // zero the k-pad slots (k 28..31 of each ws), same swizzle as data
  for (int i = tid; i < 2 * 160; i += 256) {
    const int buf = i / 160, j = i - buf * 160;
    const int b = j / 10, ws = j - b * 10;
    const int sidx = (b * 320 + ws * 32 + 28) ^ ((b & 7) << 3);
    *reinterpret_cast<short4*>(&xl[buf][sidx]) = make_short4(0, 0, 0, 0);
  }

  const int nun = (wid < 2) ? 3 : 2;             // ws units per wave (3,3,2,2)
  const int wsl[3] = {wid, wid + 4, wid + 8};    // ws 10/11 hit pad s-slots, never MFMA'd

  f32x4 acc[3];
#pragma unroll
  for (int u = 0; u < 3; ++u) acc[u] = (f32x4){0.f, 0.f, 0.f, 0.f};

  const float* xbase = x + (size_t)bg * 16 * IMG + (size_t)(hs * KK) * HW;

  float4 stgA[5], stgB[5];

#define ISSUE(STG, R)                                                       \
  _Pragma("unroll")                                                         \
  for (int j = 0; j < 5; ++j) {                                             \
    const int i = tid + 256 * j;                                            \
    if (i < 1120) {                                                         \
      const int b = i / 70, q = i - b * 70;                                 \
      STG[j] = *reinterpret_cast<const float4*>(                            \
          xbase + (size_t)b * IMG + (size_t)(R) * HW + q * 4);              \
    }                                                                       \
  }

#define COMMIT(STG, BUF)                                                    \
  _Pragma("unroll")                                                         \
  for (int j = 0; j < 5; ++j) {                                             \
    const int i = tid + 256 * j;                                            \
    if (i < 1120) {                                                         \
      const int b = i / 70, q = i - b * 70;                                 \
      const int ws = q / 7, c4 = q - ws * 7;                                \
      const int sidx = (b * 320 + ws * 32 + c4 * 4) ^ ((b & 7) << 3);       \
      uint2 pk;                                                             \
      pk.x = bits2(__float22bfloat162_rn(make_float2(STG[j].x, STG[j].y))); \
      pk.y = bits2(__float22bfloat162_rn(make_float2(STG[j].z, STG[j].w))); \
      *reinterpret_cast<uint2*>(&xl[BUF][sidx]) = pk;                       \
    }                                                                       \
  }

#define BLOAD(BFR, RR)                                                      \
  _Pragma("unroll")                                                         \
  for (int u = 0; u < 3; ++u)                                               \
    BFR[u] = *reinterpret_cast<const s16x8*>(                               \
        wbuf + (size_t)((hs * 10 + wsl[u]) * 28 + (RR)) * 512 + l15 * 32 + kg * 8);

#define MFMAS(BFR, BUF)                                                     \
  _Pragma("unroll")                                                         \
  for (int u = 0; u < 3; ++u) {                                             \
    if (u < nun) {                                                          \
      const int sidx = (l15 * 320 + wsl[u] * 32 + kg * 8) ^ ((l15 & 7) << 3); \
      const s16x8 afr = *reinterpret_cast<const s16x8*>(&xl[BUF][sidx]);    \
      acc[u] = __builtin_amdgcn_mfma_f32_16x16x32_bf16(afr, BFR[u], acc[u], 0, 0, 0); \
    }                                                                       \
  }

  // prologue: rows 0 (A) and 1 (B) in flight; commit A; lgkm barrier
  ISSUE(stgA, 0)
  ISSUE(stgB, 1)
  COMMIT(stgA, 0)            // waits A's loads only (B stays in flight)
  RAW_BARRIER();

#pragma unroll 1
  for (int r2 = 0; r2 < 14; ++r2) {
    const int re = 2 * r2;
    // ---- even phase: compute row re from xl[0] ----
    s16x8 bfrE[3];
    BLOAD(bfrE, re)
    if (re + 2 < 28) { ISSUE(stgA, re + 2) }     // newest vmem, stays in flight
    MFMAS(bfrE, 0)
    COMMIT(stgB, 1)                              // row re+1 -> buf 1
    RAW_BARRIER();
    // ---- odd phase: compute row re+1 from xl[1] ----
    const int ro = re + 1;
    s16x8 bfrO[3];
    BLOAD(bfrO, ro)
    if (ro + 2 < 28) { ISSUE(stgB, ro + 2) }
    MFMAS(bfrO, 1)
    if (r2 < 13) {
      COMMIT(stgA, 0)                            // row ro+1 -> buf 0
      RAW_BARRIER();
    }
  }

  // ---- fused epilogue ----
  // D layout: row(b-off) = kg*4+j, col(f) = l15.
  if (l15 < F_N) {
#pragma unroll
    for (int u = 0; u < 3; ++u) {
      if (u < nun) {
        const int ws = wsl[u];
        const float bias = cb[l15 * 100 + hs * 10 + ws];
        float4 hv;
        hv.x = fmaxf(acc[u][0] + bias, 0.f);
        hv.y = fmaxf(acc[u][1] + bias, 0.f);
        hv.z = fmaxf(acc[u][2] + bias, 0.f);
        hv.w = fmaxf(acc[u][3] + bias, 0.f);
        *reinterpret_cast<float4*>(&h_lds[(l15 * 10 + ws) * 16 + kg * 4]) = hv;
      }
    }
  }
  __syncthreads();

  // decoder: thread (b16, o) sums 100 d's from LDS (broadcast reads)
  if (tid < 16 * OUT_N) {
    const int b16 = tid & 15;
    const int o   = tid >> 4;
    float a = 0.f;
#pragma unroll 10
    for (int dl = 0; dl < 100; ++dl)
      a = fmaf(h_lds[dl * 16 + b16], dw_lds[o * 100 + dl], a);
    yp[(size_t)(hs * OUT_N + o) * 512 + bg * 16 + b16] = a;
  }
}

// y[b][o] = db[o] + sum over 10 hs planes; grid 20 x 256 (5120 outputs)
__global__ __launch_bounds__(256) void lcn_yred(
    const float* __restrict__ yp, const float* __restrict__ db,
    float* __restrict__ y) {
  const int idx = blockIdx.x * 256 + (int)threadIdx.x;  // 0..5119 = o*512+b
  const int o = idx >> 9;
  const int b = idx & 511;
  float a = db[o];
#pragma unroll
  for (int hs = 0; hs < 10; ++hs)
    a += yp[(size_t)(hs * OUT_N + o) * 512 + b];        // coalesced
  y[b * OUT_N + o] = a;
}

extern "C" void kernel_launch(void* const* d_in, const int* in_sizes, int n_in,
                              void* d_out, int out_size, void* d_ws, size_t ws_size,
                              hipStream_t stream) {
  const float* x  = (const float*)d_in[0];   // [512,1,280,280]
  const float* cw = (const float*)d_in[1];   // [1000,1,28,28]
  const float* cb = (const float*)d_in[2];   // [1000,1]
  const float* dw = (const float*)d_in[3];   // [10,1000]
  const float* db = (const float*)d_in[4];   // [10]
  float* y = (float*)d_out;                  // [512,10]

  float* yp   = (float*)d_ws;                // [10*10][512] = 204.8 KB
  uint4* wbuf = (uint4*)(yp + 100 * 512);    // [102][28][16][16]u32 = 2.92 MB

  wprep   <<<dim3(110), dim3(256), 0, stream>>>(cw, wbuf);
  lcn_conv<<<dim3(320), dim3(256), 0, stream>>>(x, (const unsigned short*)wbuf,
                                                cb, dw, yp);
  lcn_yred<<<dim3(20),  dim3(256), 0, stream>>>(yp, db, y);
}